// Round 11
// baseline (235.648 us; speedup 1.0000x reference)
//
#include <hip/hip_runtime.h>
#include <math.h>

// Sudoku solver v5: 2 barriers/step, fixed-slot pkey argmax, LDS-resident W2.
//  - pkey[e] (u64) = score_bits<<32 | (81-cell)<<11 | bp<<7 | e ; dead slot=0.
//    Argmax = 1 b64 gather + u64 max reduce (score desc, cell asc tie-break
//    == jnp.argmax first-occurrence). No elist compaction; ecell[] write-once.
//  - Wave-owned hs staging: wave stages exactly the rows it consumes in P2b
//    (intra-wave lgkmcnt ordering) -> no staging barrier.
//  - W2 in LDS (v4's w2r "registers" were silently rematerialized: VGPR=96<100).
//  - 2 divisions/lane (xp own prob + score) instead of 9: argmax over e9 is
//    bit-equivalent to argmax over softmax (shared positive divisor).
// Numerics: identical op composition to PASSING v4: PT dot9 k-ascending with
// exact +1 correction; h=(r+c)+b relu; a0(x,y)/a1(z,w) split then a0+a1;
// softmax expf(l-max), sum j-ascending, IEEE division; first-index tie-breaks.

#define NCELL 81
#define ND 9
#define NH 100
#define NG 27
#define GP 12          // padded gsum row stride (floats)
#define NTHREADS 256

template<int OFF>
__device__ __forceinline__ float pt_dot(const float* __restrict__ gr,
                                        const float (&w1r)[NG], int bp)
{
    float g[9];
    float4 ga = *(const float4*)gr;
    float4 gb = *(const float4*)(gr + 4);
    g[0]=ga.x; g[1]=ga.y; g[2]=ga.z; g[3]=ga.w;
    g[4]=gb.x; g[5]=gb.y; g[6]=gb.z; g[7]=gb.w;
    g[8]=gr[8];
    float acc = 0.0f;
    #pragma unroll
    for (int v = 0; v < 9; ++v)             // k-ascending, compile-time idx
        acc = fmaf(w1r[OFF + v], g[v] + ((v == bp) ? 1.0f : 0.0f), acc);
    return acc;
}

__global__ __launch_bounds__(NTHREADS, 2)
void sudoku_solver_kernel(const float* __restrict__ x_in,
                          const float* __restrict__ W1,
                          const float* __restrict__ W2,
                          float* __restrict__ out,
                          int B)
{
    __shared__ float xs[NCELL * ND];                 // board (one-hot)
    __shared__ float xp[NCELL * ND];                 // x_pred carry
    alignas(16) __shared__ float gsum[NG * GP];      // padded digit sums
    alignas(16) __shared__ float PT[NG * NH];        // group-partial dot table
    alignas(16) __shared__ float hs[NCELL * NH];     // staged h per worklist slot
    alignas(16) __shared__ float W2s[ND * NH];       // W2 rows (400B each)
    __shared__ unsigned long long pkey[NCELL];       // packed score keys by slot
    __shared__ int ecell[NCELL];                     // ce | r<<8 | c<<12 | b<<16
    __shared__ int wlist[NCELL];                     // ce | e<<8
    __shared__ int EcntS;

    const int b   = blockIdx.x;
    const int tid = threadIdx.x;
    if (b >= B) return;

    const int lane = tid & 63;
    const int wv   = tid >> 6;
    const int sgrp = lane / 9;            // cell-slot in wave, 0..7 (7 idle)
    const int vd   = lane - 9 * sgrp;     // digit owned, 0..8
    const int u    = tid % NH;            // hidden unit owned (tid<200)
    const int sub  = tid / NH;

    // ---- W1 register-resident; W2 -> LDS ----
    float w1r[NG];
    if (tid < 2 * NH) {
        #pragma unroll
        for (int k = 0; k < NG; ++k) w1r[k] = W1[u * NG + k];
    }
    for (int i = tid; i < ND * NH; i += NTHREADS) W2s[i] = W2[i];
    {
        const float* xb = x_in + (size_t)b * (NCELL * ND);
        for (int i = tid; i < NCELL * ND; i += NTHREADS) {
            float v = xb[i];
            xs[i] = v;
            xp[i] = v;
        }
    }
    for (int i = tid; i < NCELL; i += NTHREADS) pkey[i] = 0ULL;
    if (tid == 0) EcntS = 0;
    __syncthreads();

    // ---- prologue: gsum (exact ints) + empty compaction (slot assign) ----
    for (int t = tid; t < NCELL + NG * ND; t += NTHREADS) {
        if (t < NCELL) {
            const float* r = &xs[t * ND];
            float s = r[0]+r[1]+r[2]+r[3]+r[4]+r[5]+r[6]+r[7]+r[8];
            if (s == 0.0f) {
                int e = atomicAdd(&EcntS, 1);
                int rr = t / 9, cc = t % 9, bb = (rr / 3) * 3 + cc / 3;
                ecell[e] = t | (rr << 8) | (cc << 12) | (bb << 16);
                wlist[e] = t | (e << 8);
            }
        } else {
            int g = (t - NCELL) / ND;
            int v = (t - NCELL) % ND;
            float acc = 0.0f;
            if (g < 9) {
                int base = g * 9;
                #pragma unroll
                for (int j = 0; j < 9; ++j) acc += xs[(base + j) * ND + v];
            } else if (g < 18) {
                int c = g - 9;
                #pragma unroll
                for (int j = 0; j < 9; ++j) acc += xs[(j * 9 + c) * ND + v];
            } else {
                int bb = g - 18;
                int br = (bb / 3) * 3, bc2 = (bb % 3) * 3;
                #pragma unroll
                for (int j = 0; j < 9; ++j)
                    acc += xs[((br + j / 3) * 9 + (bc2 + j % 3)) * ND + v];
            }
            gsum[g * GP + v] = acc;
        }
    }
    __syncthreads();

    int E_live = EcntS;
    int W_reg  = E_live;
    if (tid < 2 * NH) {
        for (int g = sub; g < NG; g += 2) {
            float acc;
            if (g < 9)       acc = pt_dot<0>(&gsum[g * GP], w1r, -1);
            else if (g < 18) acc = pt_dot<9>(&gsum[g * GP], w1r, -1);
            else             acc = pt_dot<18>(&gsum[g * GP], w1r, -1);
            PT[g * NH + u] = acc;
        }
    }
    __syncthreads();

    int pend_cell = -1, pend_digit = 0, pend_be = 0;

    // ================= scan loop: 2 barriers/step =================
    while (E_live > 0) {
        // ---- Phase A: pending state + wave-owned staging + logits/softmax ----
        if (tid == NTHREADS - 1 && pend_cell >= 0) {    // lane63/wave3: P2b-idle
            int fr = pend_cell / 9, fc = pend_cell % 9;
            int fb = (fr / 3) * 3 + fc / 3;
            xs[pend_cell * ND + pend_digit] = 1.0f;
            gsum[fr * GP + pend_digit]        += 1.0f;  // exact int +1
            gsum[(9 + fc) * GP + pend_digit]  += 1.0f;
            gsum[(18 + fb) * GP + pend_digit] += 1.0f;
            pkey[pend_be] = 0ULL;                       // kill filled slot
        }
        const int npass  = (W_reg + 27) / 28;
        const int nchunk = npass * 7 * 25;              // this wave's chunk space
        for (int c = lane; c < nchunk; c += 64) {
            int rl = c / 25, qc = c - 25 * rl;
            int wi = (rl / 7) * 28 + wv * 7 + (rl % 7); // own rows only
            if (wi < W_reg) {
                int cell = wlist[wi] & 255;
                int r = cell / 9, cc2 = cell - 9 * r;
                int bg = 18 + (r / 3) * 3 + cc2 / 3;
                float4 hr = ((const float4*)&PT[r * NH])[qc];
                float4 hc = ((const float4*)&PT[(9 + cc2) * NH])[qc];
                float4 hb = ((const float4*)&PT[bg * NH])[qc];
                float4 h;
                h.x = fmaxf((hr.x + hc.x) + hb.x, 0.0f);
                h.y = fmaxf((hr.y + hc.y) + hb.y, 0.0f);
                h.z = fmaxf((hr.z + hc.z) + hb.z, 0.0f);
                h.w = fmaxf((hr.w + hc.w) + hb.w, 0.0f);
                ((float4*)&hs[wi * NH])[qc] = h;
            }
        }
        // consume own staged rows (compiler orders via lgkmcnt; same wave)
        for (int p = 0; p < npass; ++p) {
            int ci = p * 28 + wv * 7 + sgrp;
            if (sgrp < 7 && ci < W_reg) {
                int went = wlist[ci];
                int cell = went & 255;
                int we   = went >> 8;
                const float4* h4 = (const float4*)&hs[ci * NH];
                const float4* w4 = (const float4*)&W2s[vd * NH];
                float a0 = 0.0f, a1 = 0.0f;
                #pragma unroll
                for (int q = 0; q < 25; ++q) {
                    float4 hv = h4[q], w = w4[q];
                    a0 = fmaf(w.x, hv.x, a0);
                    a0 = fmaf(w.y, hv.y, a0);
                    a1 = fmaf(w.z, hv.z, a1);
                    a1 = fmaf(w.w, hv.w, a1);
                }
                float l_own = a0 + a1;
                float l[9];
                #pragma unroll
                for (int j = 0; j < 9; ++j) l[j] = __shfl(l_own, 9 * sgrp + j, 64);
                float m = -INFINITY;
                #pragma unroll
                for (int j = 0; j < 9; ++j) m = fmaxf(m, l[j]);
                float e9[9]; float ss = 0.0f;
                #pragma unroll
                for (int j = 0; j < 9; ++j) { e9[j] = expf(l[j] - m); ss += e9[j]; }
                // argmax over e9 == argmax over softmax (shared divisor ss>0,
                // ties preserved bitwise); first-index via strict >
                float bestE = -1.0f; int bp = 0;
                #pragma unroll
                for (int j = 0; j < 9; ++j)
                    if (e9[j] > bestE) { bestE = e9[j]; bp = j; }
                xp[cell * ND + vd] = e9[vd] / ss;       // IEEE div, like jax
                if (vd == 0) {
                    float score = e9[bp] / ss;          // == softmax max, same bits
                    unsigned lo = ((unsigned)(NCELL - cell) << 11)
                                | ((unsigned)bp << 7) | (unsigned)we;
                    pkey[we] = ((unsigned long long)__float_as_uint(score) << 32) | lo;
                }
            }
        }
        __syncthreads();

        // ---- Phase B: packed argmax + wlist rebuild + PT recompute ----
        unsigned long long key = 0ULL;
        for (int e = lane; e < NCELL; e += 64) {
            unsigned long long k = pkey[e];             // dead slots = 0
            if (k > key) key = k;
        }
        #pragma unroll
        for (int off = 32; off > 0; off >>= 1) {
            unsigned long long ok = __shfl_xor(key, off, 64);
            if (ok > key) key = ok;
        }
        const unsigned lo = (unsigned)key;
        const int be = (int)(lo & 127);
        const int bp = (int)((lo >> 7) & 15);
        const int bc = NCELL - (int)((lo >> 11) & 127);
        const int fr = bc / 9, fc = bc % 9, fb = (fr / 3) * 3 + fc / 3;

        // wlist rebuild: ballot-prefix, wave0 writes (slot-ascending), all count
        int Wn = 0;
        for (int base = 0; base < NCELL; base += 64) {
            int e = base + lane;
            bool pr = false; int ce = 0;
            if (e < NCELL && e != be && pkey[e] != 0ULL) {
                int info = ecell[e];
                ce = info & 255;
                int r = (info >> 8) & 15, c = (info >> 12) & 15, bb = (info >> 16) & 15;
                pr = (r == fr) || (c == fc) || (bb == fb);
            }
            unsigned long long mask = __ballot(pr);
            if (wv == 0 && pr) {
                int pos = Wn + (int)__popcll(mask & ((1ULL << lane) - 1ULL));
                wlist[pos] = ce | (e << 8);
            }
            Wn += (int)__popcll(mask);
        }

        // PT recompute: stale gsum + exact in-register +1 at digit bp
        if (tid < 2 * NH) {
            if (sub == 0) {
                PT[fr * NH + u]        = pt_dot<0>(&gsum[fr * GP], w1r, bp);
                PT[(18 + fb) * NH + u] = pt_dot<18>(&gsum[(18 + fb) * GP], w1r, bp);
            } else {
                PT[(9 + fc) * NH + u]  = pt_dot<9>(&gsum[(9 + fc) * GP], w1r, bp);
            }
        }

        E_live -= 1;
        pend_cell = bc; pend_digit = bp; pend_be = be;
        W_reg = Wn;
        __syncthreads();   // PT + wlist + pkey-kill visible for next Phase A
    }

    // ---- epilogue: apply final pending fill, then write out ----
    if (tid == NTHREADS - 1 && pend_cell >= 0)
        xs[pend_cell * ND + pend_digit] = 1.0f;
    __syncthreads();

    const size_t outb = (size_t)b * (NCELL * ND);
    const size_t half = (size_t)B * (NCELL * ND);
    for (int i = tid; i < NCELL * ND; i += NTHREADS) {
        out[outb + i]        = xp[i];
        out[half + outb + i] = xs[i];
    }
}

extern "C" void kernel_launch(void* const* d_in, const int* in_sizes, int n_in,
                              void* d_out, int out_size, void* d_ws, size_t ws_size,
                              hipStream_t stream)
{
    const float* x  = (const float*)d_in[0];
    // d_in[1] = constraint_mask: fixed row/col/box structure -> hardcoded
    const float* W1 = (const float*)d_in[2];
    const float* W2 = (const float*)d_in[3];
    float* out = (float*)d_out;
    const int B = in_sizes[0] / (NCELL * ND);

    sudoku_solver_kernel<<<dim3(B), dim3(NTHREADS), 0, stream>>>(x, W1, W2, out, B);
}

// Round 12
// 221.897 us; speedup vs baseline: 1.0620x; 1.0620x over previous
//
#include <hip/hip_runtime.h>
#include <math.h>

// Sudoku solver v6 = v4's PASSING 155us structure (3 barriers/step, BLOCK-WIDE
// hs staging -- v5's wave-owned staging regressed 19%, reverted) + 3 grafts:
//  g1: fixed-slot pkey[e] u64 argmax (score|cell|digit|slot) -> ONE b64 gather
//      instead of v4's chained elist[e]->escore[ce]; no compaction.
//  g2: 2 IEEE divisions/lane (xp own + score) instead of 9; argmax over e9 ==
//      argmax over softmax (shared positive divisor; v5-validated).
//  g3: W2 in LDS, 108-float padded stride (v4's w2r[25] was silently NOT
//      register-resident: VGPR=96<100). 432B stride -> worst 2-way conflict.
// Numerics: identical op composition to PASSING v4/v5: PT dot9 k-ascending
// with exact +1 correction; h=(r+c)+b relu; a0(x,y)/a1(z,w) split then a0+a1;
// softmax expf(l-max), j-ascending sum, IEEE division; first-index tie-breaks
// (score desc, cell asc via key packing).

#define NCELL 81
#define ND 9
#define NH 100
#define NG 27
#define GP 12          // padded gsum row stride (floats)
#define W2P 108        // padded W2 row stride (floats, 432B)
#define NTHREADS 256

template<int OFF>
__device__ __forceinline__ float pt_dot(const float* __restrict__ gr,
                                        const float (&w1r)[NG], int bp)
{
    float g[9];
    float4 ga = *(const float4*)gr;
    float4 gb = *(const float4*)(gr + 4);
    g[0]=ga.x; g[1]=ga.y; g[2]=ga.z; g[3]=ga.w;
    g[4]=gb.x; g[5]=gb.y; g[6]=gb.z; g[7]=gb.w;
    g[8]=gr[8];
    float acc = 0.0f;
    #pragma unroll
    for (int v = 0; v < 9; ++v)             // k-ascending, compile-time idx
        acc = fmaf(w1r[OFF + v], g[v] + ((v == bp) ? 1.0f : 0.0f), acc);
    return acc;
}

__global__ __launch_bounds__(NTHREADS, 2)
void sudoku_solver_kernel(const float* __restrict__ x_in,
                          const float* __restrict__ W1,
                          const float* __restrict__ W2,
                          float* __restrict__ out,
                          int B)
{
    __shared__ float xs[NCELL * ND];                 // board (one-hot)
    __shared__ float xp[NCELL * ND];                 // x_pred carry
    alignas(16) __shared__ float gsum[NG * GP];      // padded digit sums
    alignas(16) __shared__ float PT[NG * NH];        // group-partial dot table
    alignas(16) __shared__ float hs[NCELL * NH];     // staged h per worklist slot
    alignas(16) __shared__ float W2s[ND * W2P];      // padded W2 rows
    __shared__ unsigned long long pkey[NCELL];       // packed score keys by slot
    __shared__ int ecell[NCELL];                     // ce | r<<8 | c<<12 | b<<16
    __shared__ int wlist[NCELL];                     // ce | e<<8
    __shared__ int EcntS;

    const int b   = blockIdx.x;
    const int tid = threadIdx.x;
    if (b >= B) return;

    const int lane = tid & 63;
    const int wv   = tid >> 6;
    const int sgrp = lane / 9;            // cell-slot in wave, 0..7 (7 idle)
    const int vd   = lane - 9 * sgrp;     // digit owned, 0..8
    const int u    = tid % NH;            // hidden unit owned (tid<200)
    const int sub  = tid / NH;

    // ---- W1 register-resident; W2 -> padded LDS ----
    float w1r[NG];
    if (tid < 2 * NH) {
        #pragma unroll
        for (int k = 0; k < NG; ++k) w1r[k] = W1[u * NG + k];
    }
    for (int i = tid; i < ND * NH; i += NTHREADS) {
        int row = i / NH, col = i - row * NH;
        W2s[row * W2P + col] = W2[i];
    }
    {
        const float* xb = x_in + (size_t)b * (NCELL * ND);
        for (int i = tid; i < NCELL * ND; i += NTHREADS) {
            float v = xb[i];
            xs[i] = v;
            xp[i] = v;
        }
    }
    for (int i = tid; i < NCELL; i += NTHREADS) pkey[i] = 0ULL;
    if (tid == 0) EcntS = 0;
    __syncthreads();

    // ---- prologue: gsum (exact ints) + empty compaction (slot assign) ----
    for (int t = tid; t < NCELL + NG * ND; t += NTHREADS) {
        if (t < NCELL) {
            const float* r = &xs[t * ND];
            float s = r[0]+r[1]+r[2]+r[3]+r[4]+r[5]+r[6]+r[7]+r[8];
            if (s == 0.0f) {
                int e = atomicAdd(&EcntS, 1);
                int rr = t / 9, cc = t % 9, bb = (rr / 3) * 3 + cc / 3;
                ecell[e] = t | (rr << 8) | (cc << 12) | (bb << 16);
                wlist[e] = t | (e << 8);
            }
        } else {
            int g = (t - NCELL) / ND;
            int v = (t - NCELL) % ND;
            float acc = 0.0f;
            if (g < 9) {
                int base = g * 9;
                #pragma unroll
                for (int j = 0; j < 9; ++j) acc += xs[(base + j) * ND + v];
            } else if (g < 18) {
                int c = g - 9;
                #pragma unroll
                for (int j = 0; j < 9; ++j) acc += xs[(j * 9 + c) * ND + v];
            } else {
                int bb = g - 18;
                int br = (bb / 3) * 3, bc2 = (bb % 3) * 3;
                #pragma unroll
                for (int j = 0; j < 9; ++j)
                    acc += xs[((br + j / 3) * 9 + (bc2 + j % 3)) * ND + v];
            }
            gsum[g * GP + v] = acc;
        }
    }
    __syncthreads();

    int E_live = EcntS;
    int W_reg  = E_live;
    if (tid < 2 * NH) {
        for (int g = sub; g < NG; g += 2) {
            float acc;
            if (g < 9)       acc = pt_dot<0>(&gsum[g * GP], w1r, -1);
            else if (g < 18) acc = pt_dot<9>(&gsum[g * GP], w1r, -1);
            else             acc = pt_dot<18>(&gsum[g * GP], w1r, -1);
            PT[g * NH + u] = acc;
        }
    }
    __syncthreads();

    int pend_cell = -1, pend_digit = 0, pend_be = 0;

    // ================= scan loop: 3 barriers/step (v4 skeleton) =================
    while (E_live > 0) {
        // ---- P2a: apply pending state + BLOCK-WIDE h staging ----
        if (tid == NTHREADS - 1 && pend_cell >= 0) {
            int fr = pend_cell / 9, fc = pend_cell % 9;
            int fb = (fr / 3) * 3 + fc / 3;
            xs[pend_cell * ND + pend_digit] = 1.0f;
            gsum[fr * GP + pend_digit]        += 1.0f;  // exact int +1
            gsum[(9 + fc) * GP + pend_digit]  += 1.0f;
            gsum[(18 + fb) * GP + pend_digit] += 1.0f;
            pkey[pend_be] = 0ULL;                       // kill filled slot
        }
        for (int ch = tid; ch < W_reg * 25; ch += NTHREADS) {
            int wi = ch / 25, qc = ch - 25 * wi;
            int cell = wlist[wi] & 255;
            int r = cell / 9, c = cell - 9 * r;
            int bg = 18 + (r / 3) * 3 + c / 3;
            float4 hr = ((const float4*)&PT[r * NH])[qc];
            float4 hc = ((const float4*)&PT[(9 + c) * NH])[qc];
            float4 hb = ((const float4*)&PT[bg * NH])[qc];
            float4 h;
            h.x = fmaxf((hr.x + hc.x) + hb.x, 0.0f);
            h.y = fmaxf((hr.y + hc.y) + hb.y, 0.0f);
            h.z = fmaxf((hr.z + hc.z) + hb.z, 0.0f);
            h.w = fmaxf((hr.w + hc.w) + hb.w, 0.0f);
            ((float4*)&hs[wi * NH])[qc] = h;
        }
        __syncthreads();

        // ---- P2b: logits + softmax + pkey write ----
        const int npass = (W_reg + 27) / 28;
        for (int p = 0; p < npass; ++p) {
            int ci = p * 28 + wv * 7 + sgrp;
            if (sgrp < 7 && ci < W_reg) {
                int went = wlist[ci];
                int cell = went & 255;
                int we   = went >> 8;
                const float4* h4 = (const float4*)&hs[ci * NH];
                const float4* w4 = (const float4*)&W2s[vd * W2P];
                float a0 = 0.0f, a1 = 0.0f;
                #pragma unroll
                for (int q = 0; q < 25; ++q) {
                    float4 hv = h4[q], w = w4[q];
                    a0 = fmaf(w.x, hv.x, a0);
                    a0 = fmaf(w.y, hv.y, a0);
                    a1 = fmaf(w.z, hv.z, a1);
                    a1 = fmaf(w.w, hv.w, a1);
                }
                float l_own = a0 + a1;
                float l[9];
                #pragma unroll
                for (int j = 0; j < 9; ++j) l[j] = __shfl(l_own, 9 * sgrp + j, 64);
                float m = -INFINITY;
                #pragma unroll
                for (int j = 0; j < 9; ++j) m = fmaxf(m, l[j]);
                float e9[9]; float ss = 0.0f;
                #pragma unroll
                for (int j = 0; j < 9; ++j) { e9[j] = expf(l[j] - m); ss += e9[j]; }
                // argmax over e9 == argmax over softmax (shared divisor ss>0);
                // first-index via strict > (v5-validated)
                float bestE = -1.0f; int bp = 0;
                #pragma unroll
                for (int j = 0; j < 9; ++j)
                    if (e9[j] > bestE) { bestE = e9[j]; bp = j; }
                xp[cell * ND + vd] = e9[vd] / ss;       // IEEE div, like jax
                if (vd == 0) {
                    float score = e9[bp] / ss;          // == softmax max, same bits
                    unsigned lo = ((unsigned)(NCELL - cell) << 11)
                                | ((unsigned)bp << 7) | (unsigned)we;
                    pkey[we] = ((unsigned long long)__float_as_uint(score) << 32) | lo;
                }
            }
        }
        __syncthreads();

        // ---- P1: single-gather packed argmax + wlist rebuild + PT recompute ----
        unsigned long long key = 0ULL;
        for (int e = lane; e < NCELL; e += 64) {
            unsigned long long k = pkey[e];             // dead slots = 0
            if (k > key) key = k;
        }
        #pragma unroll
        for (int off = 32; off > 0; off >>= 1) {
            unsigned long long ok = __shfl_xor(key, off, 64);
            if (ok > key) key = ok;
        }
        const unsigned lo = (unsigned)key;
        const int be = (int)(lo & 127);
        const int bp = (int)((lo >> 7) & 15);
        const int bc = NCELL - (int)((lo >> 11) & 127);
        const int fr = bc / 9, fc = bc % 9, fb = (fr / 3) * 3 + fc / 3;

        // wlist rebuild: ballot-prefix, wave0 writes slot-ascending, all count
        int Wn = 0;
        for (int base = 0; base < NCELL; base += 64) {
            int e = base + lane;
            bool pr = false; int ce = 0;
            if (e < NCELL && e != be && pkey[e] != 0ULL) {
                int info = ecell[e];
                ce = info & 255;
                int r = (info >> 8) & 15, c = (info >> 12) & 15, bb = (info >> 16) & 15;
                pr = (r == fr) || (c == fc) || (bb == fb);
            }
            unsigned long long mask = __ballot(pr);
            if (wv == 0 && pr) {
                int pos = Wn + (int)__popcll(mask & ((1ULL << lane) - 1ULL));
                wlist[pos] = ce | (e << 8);
            }
            Wn += (int)__popcll(mask);
        }

        // PT recompute: stale gsum + exact in-register +1 at digit bp
        if (tid < 2 * NH) {
            if (sub == 0) {
                PT[fr * NH + u]        = pt_dot<0>(&gsum[fr * GP], w1r, bp);
                PT[(18 + fb) * NH + u] = pt_dot<18>(&gsum[(18 + fb) * GP], w1r, bp);
            } else {
                PT[(9 + fc) * NH + u]  = pt_dot<9>(&gsum[(9 + fc) * GP], w1r, bp);
            }
        }

        E_live -= 1;
        pend_cell = bc; pend_digit = bp; pend_be = be;
        W_reg = Wn;
        __syncthreads();   // PT + wlist + pkey visible for next P2a
    }

    // ---- epilogue: apply final pending fill, then write out ----
    if (tid == NTHREADS - 1 && pend_cell >= 0)
        xs[pend_cell * ND + pend_digit] = 1.0f;
    __syncthreads();

    const size_t outb = (size_t)b * (NCELL * ND);
    const size_t half = (size_t)B * (NCELL * ND);
    for (int i = tid; i < NCELL * ND; i += NTHREADS) {
        out[outb + i]        = xp[i];
        out[half + outb + i] = xs[i];
    }
}

extern "C" void kernel_launch(void* const* d_in, const int* in_sizes, int n_in,
                              void* d_out, int out_size, void* d_ws, size_t ws_size,
                              hipStream_t stream)
{
    const float* x  = (const float*)d_in[0];
    // d_in[1] = constraint_mask: fixed row/col/box structure -> hardcoded
    const float* W1 = (const float*)d_in[2];
    const float* W2 = (const float*)d_in[3];
    float* out = (float*)d_out;
    const int B = in_sizes[0] / (NCELL * ND);

    sudoku_solver_kernel<<<dim3(B), dim3(NTHREADS), 0, stream>>>(x, W1, W2, out, B);
}